// Round 1
// baseline (22186.725 us; speedup 1.0000x reference)
//
#include <hip/hip_runtime.h>

// ---------------------------------------------------------------------------
// LSTM (L=4, B=64, T=256, H=D=1024, O=512) via diagonal-wavefront multi-launch.
// Cell (t,l): gates[64,4096] = [inp|h_prev][64,2048] @ Wcat[l][4096,2048]^T.
// Wcat rows gate-interleaved: row 4u+g = gate g of hidden unit u, so one wave's
// N-slice contains complete (i,f,g,o) quads -> shuffle epilogue, no gates-LDS.
// bf16 weights/activations, fp32 accumulation (MFMA 16x16x32 bf16).
// ---------------------------------------------------------------------------

typedef short           bf16x8 __attribute__((ext_vector_type(8)));
typedef unsigned short  u16x8  __attribute__((ext_vector_type(8)));
typedef float           f32x4  __attribute__((ext_vector_type(4)));

static constexpr int kB  = 64;     // batch
static constexpr int kT  = 256;    // seq len
static constexpr int kH  = 1024;   // hidden
static constexpr int kL  = 4;      // layers
static constexpr int kNG = 4096;   // 4*H gate rows
static constexpr int kK2 = 2048;   // concat K
static constexpr int kO  = 512;    // output dim

// ws layout (bytes)
static constexpr size_t OFF_W    = 0;                         // bf16 Wcat   67,108,864
static constexpr size_t OFF_BIAS = 67108864;                  // f32 bias        65,536
static constexpr size_t OFF_H    = 67174400;                  // bf16 h[2][L][B][H] 1 MB
static constexpr size_t OFF_C    = 68222976;                  // f32  c[L][B][H]    1 MB

static __device__ __forceinline__ unsigned short f2bf(float f) {
  unsigned int u = __float_as_uint(f);
  u += 0x7fffu + ((u >> 16) & 1u);          // RNE
  return (unsigned short)(u >> 16);
}
static __device__ __forceinline__ float bf2f(unsigned short s) {
  return __uint_as_float(((unsigned int)s) << 16);
}
static __device__ __forceinline__ float sigm_(float x) {
  return 1.0f / (1.0f + __expf(-x));
}
static __device__ __forceinline__ float tanh_(float x) {
  return 1.0f - 2.0f / (__expf(2.0f * x) + 1.0f);
}

// --- prepack: Wcat[l][4u+g][k] = bf16( k<1024 ? W_ih[l][g*1024+u][k] : W_hh[...][k-1024] )
__global__ __launch_bounds__(256) void prepack_w(const float* __restrict__ Wih,
                                                 const float* __restrict__ Whh,
                                                 unsigned short* __restrict__ Wcat) {
  const size_t total = (size_t)kL * kNG * kK2;
  for (size_t e = (size_t)blockIdx.x * 256 + threadIdx.x; e < total;
       e += (size_t)gridDim.x * 256) {
    int k = (int)(e & 2047);
    int n = (int)((e >> 11) & 4095);
    int l = (int)(e >> 23);
    int r = (n & 3) * 1024 + (n >> 2);      // source row in [4H,*]
    float v = (k < 1024) ? Wih[((size_t)l * kNG + r) * 1024 + k]
                         : Whh[((size_t)l * kNG + r) * 1024 + (k - 1024)];
    Wcat[e] = f2bf(v);
  }
}

__global__ __launch_bounds__(256) void prepack_bias(const float* __restrict__ bih,
                                                    const float* __restrict__ bhh,
                                                    float* __restrict__ bias) {
  int e = blockIdx.x * 256 + threadIdx.x;   // 16384 exact
  int l = e >> 12, n = e & 4095;
  int r = (n & 3) * 1024 + (n >> 2);
  bias[e] = bih[l * kNG + r] + bhh[l * kNG + r];
}

// --- one anti-diagonal d: cells (t = d - l, l) for l = blockIdx.y
__global__ __launch_bounds__(256) void lstm_diag(
    const unsigned short* __restrict__ Wcat, const float* __restrict__ bias,
    const float* __restrict__ x, unsigned short* __restrict__ hbuf,
    float* __restrict__ cbuf, int d) {
  const int l = blockIdx.y;
  const int t = d - l;
  if (t < 0 || t >= kT) return;

  const int tid  = threadIdx.x;
  const int lane = tid & 63;
  const int wave = tid >> 6;
  const int quad = lane >> 4;
  const int l15  = lane & 15;

  __shared__ unsigned short Alds[2][64 * 72];   // padded stride 72 elems (144 B)

  const unsigned short* inp_h =
      hbuf + (size_t)((t & 1) * kL + (l > 0 ? l - 1 : 0)) * (kB * kH);
  const unsigned short* hpr =
      hbuf + (size_t)(((t + 1) & 1) * kL + l) * (kB * kH);

  const int nwave = blockIdx.x * 256 + wave * 64;  // wave's gate-row base
  const unsigned short* wrow = Wcat + ((size_t)(l * kNG + nwave + l15)) * kK2;

  float bs[4];
#pragma unroll
  for (int nt = 0; nt < 4; ++nt) bs[nt] = bias[l * kNG + nwave + nt * 16 + l15];

  f32x4 acc[4][4] = {};

  // stage one K-chunk (64 k) of A = [inp | h_prev] into LDS buf
  auto stage = [&](int kc, int buf) {
    if (l == 0 && kc < 16) {                 // from fp32 x[b][t][d]
#pragma unroll
      for (int i = tid; i < 512; i += 256) {
        int m = i >> 3, kp = (i & 7) * 8;
        const float* s = x + ((size_t)m * kT + t) * kH + kc * 64 + kp;
        float4 f0 = *(const float4*)s;
        float4 f1 = *(const float4*)(s + 4);
        u16x8 v;
        v[0] = f2bf(f0.x); v[1] = f2bf(f0.y); v[2] = f2bf(f0.z); v[3] = f2bf(f0.w);
        v[4] = f2bf(f1.x); v[5] = f2bf(f1.y); v[6] = f2bf(f1.z); v[7] = f2bf(f1.w);
        *(u16x8*)&Alds[buf][m * 72 + kp] = v;
      }
    } else {                                  // bf16 h rows
      const unsigned short* src = (kc < 16) ? inp_h : hpr;
      int off = (kc < 16) ? kc * 64 : (kc - 16) * 64;
#pragma unroll
      for (int i = tid; i < 512; i += 256) {
        int m = i >> 3, kp = (i & 7) * 8;
        u16x8 v = *(const u16x8*)(src + (size_t)m * kH + off + kp);
        *(u16x8*)&Alds[buf][m * 72 + kp] = v;
      }
    }
  };

  auto loadb = [&](int kc, bf16x8 (&bb)[2][4]) {
#pragma unroll
    for (int ks = 0; ks < 2; ++ks)
#pragma unroll
      for (int nt = 0; nt < 4; ++nt)
        bb[ks][nt] = *(const bf16x8*)(wrow + (size_t)nt * 16 * kK2 +
                                      kc * 64 + ks * 32 + quad * 8);
  };

  bf16x8 bcur[2][4], bnxt[2][4];
  loadb(0, bcur);
  stage(0, 0);
  __syncthreads();

  for (int kc = 0; kc < 32; ++kc) {
    const int cb = kc & 1;
    if (kc < 31) {
      stage(kc + 1, cb ^ 1);
      loadb(kc + 1, bnxt);
    }
#pragma unroll
    for (int ks = 0; ks < 2; ++ks) {
      bf16x8 af[4];
#pragma unroll
      for (int mt = 0; mt < 4; ++mt)
        af[mt] = *(const bf16x8*)&Alds[cb][(mt * 16 + l15) * 72 + ks * 32 + quad * 8];
#pragma unroll
      for (int mt = 0; mt < 4; ++mt)
#pragma unroll
        for (int nt = 0; nt < 4; ++nt)
          acc[mt][nt] = __builtin_amdgcn_mfma_f32_16x16x32_bf16(
              af[mt], bcur[ks][nt], acc[mt][nt], 0, 0, 0);
    }
#pragma unroll
    for (int ks = 0; ks < 2; ++ks)
#pragma unroll
      for (int nt = 0; nt < 4; ++nt) bcur[ks][nt] = bnxt[ks][nt];
    __syncthreads();
  }

  // epilogue: lanes 4u+{0,1,2,3} hold (i,f,g,o) of unit u; D[m=quad*4+r][n=lane&15]
  const int g = lane & 3;
  unsigned short* hout = hbuf + (size_t)((t & 1) * kL + l) * (kB * kH);
#pragma unroll
  for (int mt = 0; mt < 4; ++mt)
#pragma unroll
    for (int nt = 0; nt < 4; ++nt)
#pragma unroll
      for (int r = 0; r < 4; ++r) {
        float xg = acc[mt][nt][r] + bs[nt];
        float av = (g == 2) ? tanh_(xg) : sigm_(xg);
        float gv = __shfl_xor(av, 2);
        float fv = __shfl_xor(av, 1);
        float ov = __shfl_xor(av, 3);
        if (g == 0) {                        // lane holds i; combine
          int m = mt * 16 + quad * 4 + r;
          int u = (nwave + nt * 16 + l15) >> 2;
          size_t ci = ((size_t)l * kB + m) * kH + u;
          float cn = fv * cbuf[ci] + av * gv;
          cbuf[ci] = cn;
          hout[(size_t)m * kH + u] = f2bf(ov * tanh_(cn));
        }
      }
}

// --- final FC: out[64,512] = h[last][3] @ W_fc^T + b_fc
__global__ __launch_bounds__(256) void lstm_fc(const unsigned short* __restrict__ h3,
                                               const float* __restrict__ Wfc,
                                               const float* __restrict__ bfc,
                                               float* __restrict__ out) {
  int gt = blockIdx.x * 256 + threadIdx.x;  // 32768 exact
  int b = gt >> 9, o = gt & 511;
  const unsigned short* hr = h3 + (size_t)b * kH;
  const float* wr = Wfc + (size_t)o * kH;
  float acc = bfc[o];
#pragma unroll 4
  for (int k = 0; k < kH; k += 8) {
    u16x8 hv = *(const u16x8*)(hr + k);
    float4 w0 = *(const float4*)(wr + k);
    float4 w1 = *(const float4*)(wr + k + 4);
    acc += bf2f(hv[0]) * w0.x + bf2f(hv[1]) * w0.y + bf2f(hv[2]) * w0.z +
           bf2f(hv[3]) * w0.w + bf2f(hv[4]) * w1.x + bf2f(hv[5]) * w1.y +
           bf2f(hv[6]) * w1.z + bf2f(hv[7]) * w1.w;
  }
  out[gt] = acc;
}

extern "C" void kernel_launch(void* const* d_in, const int* in_sizes, int n_in,
                              void* d_out, int out_size, void* d_ws, size_t ws_size,
                              hipStream_t stream) {
  (void)in_sizes; (void)n_in; (void)out_size; (void)ws_size;
  const float* x   = (const float*)d_in[0];
  const float* Wih = (const float*)d_in[1];
  const float* Whh = (const float*)d_in[2];
  const float* bih = (const float*)d_in[3];
  const float* bhh = (const float*)d_in[4];
  const float* Wfc = (const float*)d_in[5];
  const float* bfc = (const float*)d_in[6];
  float* out = (float*)d_out;

  char* ws = (char*)d_ws;
  unsigned short* Wcat = (unsigned short*)(ws + OFF_W);
  float*          bias = (float*)(ws + OFF_BIAS);
  unsigned short* hbuf = (unsigned short*)(ws + OFF_H);
  float*          cbuf = (float*)(ws + OFF_C);

  prepack_w<<<8192, 256, 0, stream>>>(Wih, Whh, Wcat);
  prepack_bias<<<64, 256, 0, stream>>>(bih, bhh, bias);
  // zero h (both slots) and c; they are contiguous: 1 MB + 1 MB
  hipMemsetAsync(ws + OFF_H, 0, 2097152, stream);

  for (int d = 0; d < kT + kL - 1; ++d)
    lstm_diag<<<dim3(16, 4), 256, 0, stream>>>(Wcat, bias, x, hbuf, cbuf, d);

  lstm_fc<<<128, 256, 0, stream>>>(hbuf + (size_t)7 * kB * kH, Wfc, bfc, out);
}

// Round 2
// 5968.970 us; speedup vs baseline: 3.7170x; 3.7170x over previous
//
#include <hip/hip_runtime.h>

// ---------------------------------------------------------------------------
// LSTM (L=4, B=64, T=256, H=D=1024, O=512), diagonal-wavefront multi-launch.
// Round 2: 256 WGs (64/layer, N=64 gate-rows each), K-split-4 across waves,
// direct global->VGPR MFMA fragment loads (no LDS staging, no K-loop barriers),
// LDS only for the 4-way K-split reduction. x preconverted to bf16.
// Wcat rows gate-interleaved: row 4u+g = gate g of unit u.
// ---------------------------------------------------------------------------

typedef short           bf16x8 __attribute__((ext_vector_type(8)));
typedef unsigned short  u16x8  __attribute__((ext_vector_type(8)));
typedef float           f32x4  __attribute__((ext_vector_type(4)));

static constexpr int kB  = 64;
static constexpr int kT  = 256;
static constexpr int kH  = 1024;
static constexpr int kL  = 4;
static constexpr int kNG = 4096;   // 4*H
static constexpr int kK2 = 2048;   // concat K

// ws layout (bytes)
static constexpr size_t OFF_W    = 0;           // bf16 Wcat  67,108,864
static constexpr size_t OFF_BIAS = 67108864;    // f32 bias       65,536
static constexpr size_t OFF_XB   = 67174400;    // bf16 x     33,554,432
static constexpr size_t OFF_H    = 100728832;   // bf16 h[2][L][B][H] 1 MB
static constexpr size_t OFF_C    = 101777408;   // f32  c[L][B][H]    1 MB

static __device__ __forceinline__ unsigned short f2bf(float f) {
  unsigned int u = __float_as_uint(f);
  u += 0x7fffu + ((u >> 16) & 1u);  // RNE
  return (unsigned short)(u >> 16);
}
static __device__ __forceinline__ float bf2f(unsigned short s) {
  return __uint_as_float(((unsigned int)s) << 16);
}
static __device__ __forceinline__ float sigm_(float x) {
  return 1.0f / (1.0f + __expf(-x));
}
static __device__ __forceinline__ float tanh_(float x) {
  return 1.0f - 2.0f / (__expf(2.0f * x) + 1.0f);
}

__global__ __launch_bounds__(256) void prepack_w(const float* __restrict__ Wih,
                                                 const float* __restrict__ Whh,
                                                 unsigned short* __restrict__ Wcat) {
  const size_t total = (size_t)kL * kNG * kK2;
  for (size_t e = (size_t)blockIdx.x * 256 + threadIdx.x; e < total;
       e += (size_t)gridDim.x * 256) {
    int k = (int)(e & 2047);
    int n = (int)((e >> 11) & 4095);
    int l = (int)(e >> 23);
    int r = (n & 3) * 1024 + (n >> 2);
    float v = (k < 1024) ? Wih[((size_t)l * kNG + r) * 1024 + k]
                         : Whh[((size_t)l * kNG + r) * 1024 + (k - 1024)];
    Wcat[e] = f2bf(v);
  }
}

__global__ __launch_bounds__(256) void prepack_bias(const float* __restrict__ bih,
                                                    const float* __restrict__ bhh,
                                                    float* __restrict__ bias) {
  int e = blockIdx.x * 256 + threadIdx.x;  // 16384 exact
  int l = e >> 12, n = e & 4095;
  int r = (n & 3) * 1024 + (n >> 2);
  bias[e] = bih[l * kNG + r] + bhh[l * kNG + r];
}

__global__ __launch_bounds__(256) void prepack_x(const float* __restrict__ x,
                                                 unsigned short* __restrict__ xb) {
  size_t e = ((size_t)blockIdx.x * 256 + threadIdx.x) * 8;  // grid 8192 covers 16M
  float4 f0 = *(const float4*)(x + e);
  float4 f1 = *(const float4*)(x + e + 4);
  u16x8 v;
  v[0] = f2bf(f0.x); v[1] = f2bf(f0.y); v[2] = f2bf(f0.z); v[3] = f2bf(f0.w);
  v[4] = f2bf(f1.x); v[5] = f2bf(f1.y); v[6] = f2bf(f1.z); v[7] = f2bf(f1.w);
  *(u16x8*)(xb + e) = v;
}

// --- one anti-diagonal d. 256 WGs: layer l = bid>>6, N-slab = bid&63.
__global__ __launch_bounds__(256) void lstm_diag(
    const unsigned short* __restrict__ Wcat, const float* __restrict__ bias,
    const unsigned short* __restrict__ xb, unsigned short* __restrict__ hbuf,
    float* __restrict__ cbuf, int d) {
  const int l = blockIdx.x >> 6;
  const int t = d - l;
  if (t < 0 || t >= kT) return;
  const int nwg = (blockIdx.x & 63) * 64;

  const int tid  = threadIdx.x;
  const int lane = tid & 63;
  const int w    = tid >> 6;      // K-split index: K range [w*512, w*512+512)
  const int quad = lane >> 4;
  const int l15  = lane & 15;

  // A source for this wave's K range
  const unsigned short* srcA;
  size_t strideA;
  if (w < 2) {
    if (l == 0) { srcA = xb + (size_t)t * kH + w * 512; strideA = (size_t)kT * kH; }
    else {
      srcA = hbuf + (size_t)((t & 1) * kL + (l - 1)) * (kB * kH) + w * 512;
      strideA = kH;
    }
  } else {
    srcA = hbuf + (size_t)(((t + 1) & 1) * kL + l) * (kB * kH) + (w - 2) * 512;
    strideA = kH;
  }

  // per-mt / per-nt base pointers (immediate offsets cover kc*64B <= 960)
  const unsigned short* pA[4];
  const unsigned short* pB[4];
  {
    const unsigned short* wrow =
        Wcat + ((size_t)(l * kNG + nwg + l15)) * kK2 + w * 512 + quad * 8;
#pragma unroll
    for (int i = 0; i < 4; ++i) {
      pA[i] = srcA + (size_t)(i * 16 + l15) * strideA + quad * 8;
      pB[i] = wrow + (size_t)i * 16 * kK2;
    }
  }

  f32x4 acc[4][4] = {};
  bf16x8 a0[4], b0[4], a1[4], b1[4];

#pragma unroll
  for (int i = 0; i < 4; ++i) { a0[i] = *(const bf16x8*)(pA[i]); b0[i] = *(const bf16x8*)(pB[i]); }

#pragma unroll
  for (int kc = 0; kc < 16; ++kc) {
    bf16x8* ac = (kc & 1) ? a1 : a0;
    bf16x8* bc = (kc & 1) ? b1 : b0;
    bf16x8* an = (kc & 1) ? a0 : a1;
    bf16x8* bn = (kc & 1) ? b0 : b1;
    if (kc < 15) {
#pragma unroll
      for (int i = 0; i < 4; ++i) {
        an[i] = *(const bf16x8*)(pA[i] + (kc + 1) * 32);
        bn[i] = *(const bf16x8*)(pB[i] + (kc + 1) * 32);
      }
    }
#pragma unroll
    for (int mt = 0; mt < 4; ++mt)
#pragma unroll
      for (int nt = 0; nt < 4; ++nt)
        acc[mt][nt] = __builtin_amdgcn_mfma_f32_16x16x32_bf16(ac[mt], bc[nt],
                                                              acc[mt][nt], 0, 0, 0);
  }

  // ---- K-split reduction through LDS (stride 68 floats: ~2-way banks) ----
  __shared__ float part[2][64][68];  // 34,816 B

  if (w >= 2) {
    float* p = &part[w - 2][0][0];
#pragma unroll
    for (int mt = 0; mt < 4; ++mt)
#pragma unroll
      for (int nt = 0; nt < 4; ++nt)
#pragma unroll
        for (int r = 0; r < 4; ++r)
          p[(mt * 16 + quad * 4 + r) * 68 + nt * 16 + l15] = acc[mt][nt][r];
  }
  __syncthreads();
  if (w < 2) {
    const float* p = &part[w][0][0];
#pragma unroll
    for (int mt = 0; mt < 4; ++mt)
#pragma unroll
      for (int nt = 0; nt < 4; ++nt)
#pragma unroll
        for (int r = 0; r < 4; ++r)
          acc[mt][nt][r] += p[(mt * 16 + quad * 4 + r) * 68 + nt * 16 + l15];
  }
  __syncthreads();
  if (w < 2) {
    float* p = &part[w][0][0];
#pragma unroll
    for (int mt = 0; mt < 4; ++mt)
#pragma unroll
      for (int nt = 0; nt < 4; ++nt)
#pragma unroll
        for (int r = 0; r < 4; ++r)
          p[(mt * 16 + quad * 4 + r) * 68 + nt * 16 + l15] = acc[mt][nt][r];
  }
  __syncthreads();

  // ---- epilogue: wave w handles batch rows [w*16, w*16+16) ----
  const int m  = (w << 4) | (lane >> 2);  // batch index
  const int ug = lane & 3;
  unsigned short* hout = hbuf + (size_t)((t & 1) * kL + l) * (kB * kH);
#pragma unroll
  for (int j = 0; j < 4; ++j) {
    int ul = 4 * j + ug;           // local unit 0..15
    int nb = 4 * ul;               // local gate base
    float4 p0 = *(const float4*)&part[0][m][nb];
    float4 p1 = *(const float4*)&part[1][m][nb];
    float4 bs = *(const float4*)&bias[l * kNG + nwg + nb];
    float gi = sigm_(p0.x + p1.x + bs.x);
    float gf = sigm_(p0.y + p1.y + bs.y);
    float gg = tanh_(p0.z + p1.z + bs.z);
    float go = sigm_(p0.w + p1.w + bs.w);
    int u = (nwg >> 2) + ul;       // global hidden unit
    size_t ci = ((size_t)l * kB + m) * kH + u;
    float cn = gf * cbuf[ci] + gi * gg;
    cbuf[ci] = cn;
    hout[(size_t)m * kH + u] = f2bf(go * tanh_(cn));
  }
}

// --- final FC: out[64,512] = h[last] @ W_fc^T + b_fc
__global__ __launch_bounds__(256) void lstm_fc(const unsigned short* __restrict__ h3,
                                               const float* __restrict__ Wfc,
                                               const float* __restrict__ bfc,
                                               float* __restrict__ out) {
  int gt = blockIdx.x * 256 + threadIdx.x;  // 32768 exact
  int b = gt >> 9, o = gt & 511;
  const unsigned short* hr = h3 + (size_t)b * kH;
  const float* wr = Wfc + (size_t)o * kH;
  float acc = bfc[o];
#pragma unroll 4
  for (int k = 0; k < kH; k += 8) {
    u16x8 hv = *(const u16x8*)(hr + k);
    float4 w0 = *(const float4*)(wr + k);
    float4 w1 = *(const float4*)(wr + k + 4);
    acc += bf2f(hv[0]) * w0.x + bf2f(hv[1]) * w0.y + bf2f(hv[2]) * w0.z +
           bf2f(hv[3]) * w0.w + bf2f(hv[4]) * w1.x + bf2f(hv[5]) * w1.y +
           bf2f(hv[6]) * w1.z + bf2f(hv[7]) * w1.w;
  }
  out[gt] = acc;
}

extern "C" void kernel_launch(void* const* d_in, const int* in_sizes, int n_in,
                              void* d_out, int out_size, void* d_ws, size_t ws_size,
                              hipStream_t stream) {
  (void)in_sizes; (void)n_in; (void)out_size; (void)ws_size;
  const float* x   = (const float*)d_in[0];
  const float* Wih = (const float*)d_in[1];
  const float* Whh = (const float*)d_in[2];
  const float* bih = (const float*)d_in[3];
  const float* bhh = (const float*)d_in[4];
  const float* Wfc = (const float*)d_in[5];
  const float* bfc = (const float*)d_in[6];
  float* out = (float*)d_out;

  char* ws = (char*)d_ws;
  unsigned short* Wcat = (unsigned short*)(ws + OFF_W);
  float*          bias = (float*)(ws + OFF_BIAS);
  unsigned short* xb   = (unsigned short*)(ws + OFF_XB);
  unsigned short* hbuf = (unsigned short*)(ws + OFF_H);
  float*          cbuf = (float*)(ws + OFF_C);

  prepack_w<<<8192, 256, 0, stream>>>(Wih, Whh, Wcat);
  prepack_bias<<<64, 256, 0, stream>>>(bih, bhh, bias);
  prepack_x<<<8192, 256, 0, stream>>>(x, xb);
  hipMemsetAsync(ws + OFF_H, 0, 2097152, stream);  // h (both slots) + c

  for (int d = 0; d < kT + kL - 1; ++d)
    lstm_diag<<<256, 256, 0, stream>>>(Wcat, bias, xb, hbuf, cbuf, d);

  lstm_fc<<<128, 256, 0, stream>>>(hbuf + (size_t)7 * kB * kH, Wfc, bfc, out);
}